// Round 5
// baseline (171.921 us; speedup 1.0000x reference)
//
#include <hip/hip_runtime.h>
#include <math.h>

// N=8192 rows, D=256, fp32 in, scalar fp32 out.
// out = mean_i ||v0_i-v1_i|| + 0.5*(mean_i log S0_i + mean_i log S1_i) - log(N-1)
// S_i = sum_{j!=i} exp(-sqrt(max(sq_i+sq_j-2*z_i.z_j,0)))
//
// Round 19: paired-quadrant passes + occupancy pin. r18 post-mortem: VGPR
// drifted 100->128 (outer tile loop) -> 4 blocks/CU -> entropy 47.5us. The
// dominant idle is B-fragment reload latency: at VGPR~100 the compiler
// reloads bF from L2 inside EVERY quadrant's s-loop (64 exposed loads/tile,
// 4 MFMAs each). Now 2 quadrants share each B-pass: per s, 4 B-loads feed 8
// MFMAs (acc0+acc1); B-reload events halve, amortization doubles, live set
// ~96 regs. __launch_bounds__(256,5) pins 5 blocks/CU (VGPR<=102). Grid back
// to r16's proven 2-tile/1056-segment layout. Fused finalize retained.

#define D_DIM 256
#define NB 64                 // 8192/128 panels
#define NSEG 1056             // sum over rows bi of ceil((64-bi)/2)
#define S_Q 26.0f             // i8 quant scale
#define LOG2E2 2.0813689810f  // (log2 e)^2
#define LP 65                 // padded LDS pitch in float4 (prep)

typedef int i32x4 __attribute__((ext_vector_type(4)));
typedef unsigned int u32;
#define AS1 __attribute__((address_space(1)))
#define AS3 __attribute__((address_space(3)))

__device__ inline void load_lds16(const void* g, void* l) {
  __builtin_amdgcn_global_load_lds((const AS1 u32*)g, (AS3 u32*)l, 16, 0, 0);
}

__device__ inline int q8(float x) {
  return __float2int_rn(fminf(fmaxf(x * S_Q, -127.0f), 127.0f));
}
__device__ inline u32 q8x4(const float4 f) {
  return (u32)(q8(f.x) & 255) | ((u32)(q8(f.y) & 255) << 8) |
         ((u32)(q8(f.z) & 255) << 16) | ((u32)(q8(f.w) & 255) << 24);
}

// G(M) = sum_{L=1..M} ceil(L/2); segment-count prefix helper.
__device__ inline int Gfun(int M) {
  const int m = M >> 1;
  return (M & 1) ? (m + 1) * (m + 1) : m * (m + 1);
}

// One block per 16-row tile R. Stages both views' rows in LDS (padded pitch),
// emits packed fragment-ordered i8 planes, computes prescaled sq norms +
// align parts, zeroes S. Block 0 also zeroes the finalize totals/ticket.
// Plane layout: 16B chunk index (R*4 + s)*64 + q*16 + rr holds elements
// (row = R*16 + rr, k = s*64 + q*16 + j), j=0..15 -- one lane-operand of
// mfma_i32_16x16x64_i8 per chunk; one wave-fragment per 1KB block.
__global__ __launch_bounds__(256) void prep(
    const float* __restrict__ v0, const float* __restrict__ v1,
    unsigned char* __restrict__ ph0, unsigned char* __restrict__ ph1,
    float* __restrict__ sq0, float* __restrict__ sq1,
    float* __restrict__ S0, float* __restrict__ S1,
    float* __restrict__ align_part,
    double* __restrict__ totals, int* __restrict__ ticket) {
  __shared__ float4 l0[16 * LP], l1[16 * LP];   // 16 rows, padded pitch
  __shared__ float red0[4][16], red1[4][16], red2[4][16];
  const int R = blockIdx.x;
  const int t = threadIdx.x;

  if (R == 0 && t == 0) { totals[0] = 0.0; totals[1] = 0.0; ticket[0] = 0; }

  // coalesced load: 16 rows x 64 float4 per view (stored at padded pitch)
  #pragma unroll
  for (int p = 0; p < 4; ++p) {
    const int slot = t + p * 256;
    const int r = slot >> 6, col = slot & 63;
    const size_t g = (size_t)(R * 16 + r) * 64 + col;
    l0[r * LP + col] = ((const float4*)v0)[g];
    l1[r * LP + col] = ((const float4*)v1)[g];
  }
  __syncthreads();

  // quant+pack: thread t -> row rr = t&15, k-group c = t>>4 (16 elements)
  {
    const int rr = t & 15, c = t >> 4;
    const int s = c >> 2, q = c & 3;
    const int li = rr * LP + c * 4;       // float4 index of k = c*16
    uint4 u0, u1;
    u0.x = q8x4(l0[li + 0]); u0.y = q8x4(l0[li + 1]);
    u0.z = q8x4(l0[li + 2]); u0.w = q8x4(l0[li + 3]);
    u1.x = q8x4(l1[li + 0]); u1.y = q8x4(l1[li + 1]);
    u1.z = q8x4(l1[li + 2]); u1.w = q8x4(l1[li + 3]);
    const size_t dst = (size_t)(R * 4 + s) * 64 + q * 16 + rr;
    ((uint4*)ph0)[dst] = u0;
    ((uint4*)ph1)[dst] = u1;
  }

  // norms: thread t sums 16 elements of row (t&15), segment (t>>4)
  {
    const int rr = t & 15;
    const int base = rr * LP + (t >> 4) * 4;
    float s0p = 0.f, s1p = 0.f, s2p = 0.f;
    #pragma unroll
    for (int c = 0; c < 4; ++c) {
      const float4 a = l0[base + c], b = l1[base + c];
      s0p += a.x * a.x + a.y * a.y + a.z * a.z + a.w * a.w;
      s1p += b.x * b.x + b.y * b.y + b.z * b.z + b.w * b.w;
      const float dx = a.x - b.x, dy = a.y - b.y, dz = a.z - b.z, dw = a.w - b.w;
      s2p += dx * dx + dy * dy + dz * dz + dw * dw;
    }
    s0p += __shfl_xor(s0p, 16, 64); s0p += __shfl_xor(s0p, 32, 64);
    s1p += __shfl_xor(s1p, 16, 64); s1p += __shfl_xor(s1p, 32, 64);
    s2p += __shfl_xor(s2p, 16, 64); s2p += __shfl_xor(s2p, 32, 64);
    const int w = t >> 6, lane = t & 63;
    if (lane < 16) { red0[w][lane] = s0p; red1[w][lane] = s1p; red2[w][lane] = s2p; }
  }
  __syncthreads();
  if (t < 16) {
    const int row = R * 16 + t;
    const float a0 = red0[0][t] + red0[1][t] + red0[2][t] + red0[3][t];
    const float a1 = red1[0][t] + red1[1][t] + red1[2][t] + red1[3][t];
    const float a2 = red2[0][t] + red2[1][t] + red2[2][t] + red2[3][t];
    sq0[row] = a0 * LOG2E2;               // prescaled: epilogue works in log2 units
    sq1[row] = a1 * LOG2E2;
    align_part[row] = sqrtf(a2);
    S0[row] = 0.0f;
    S1[row] = 0.0f;
  }
}

// Persistent 2-tile row segments; grid (NSEG, 2=view). 4 waves in 2x2,
// pinned to 5 blocks/CU (VGPR<=102) so 20 waves/CU hide vmem latency.
// Per tile: two paired-quadrant passes; each pass streams the 16 B
// fragments ONCE (4 loads per s-chunk feeding 8 MFMAs into two quadrant
// accumulators), then runs both quadrants' epilogues -- which overlap the
// next pass's B loads (no barriers inside or between tiles).
__global__ __launch_bounds__(256, 5) void entropy_tile(
    const unsigned char* __restrict__ ph0, const unsigned char* __restrict__ ph1,
    const float* __restrict__ sq0, const float* __restrict__ sq1,
    float* __restrict__ S0, float* __restrict__ S1) {
  const unsigned char* __restrict__ ph = blockIdx.y ? ph1 : ph0;
  const float* __restrict__ sq = blockIdx.y ? sq1 : sq0;
  float* __restrict__ S        = blockIdx.y ? S1 : S0;

  // decode segment -> (bi, q): row bi has ceil((64-bi)/2) segments;
  // prefix P(bi) = NSEG - G(64-bi).
  const int lin = blockIdx.x;
  int bi = 0;
  while (NSEG - Gfun(64 - (bi + 1)) <= lin) ++bi;
  const int q = lin - (NSEG - Gfun(64 - bi));
  const int bj0 = bi + 2 * q;

  // 32 KB: the A panel (i8, fragment order). Front 17408 B reused as epilogue
  // scratch (guarded by the post-tiles barrier).
  __shared__ __align__(16) char smem[32768];
  float* swp = (float*)smem;

  const int t = threadIdx.x, lane = t & 63, w = t >> 6;
  const int wi = w >> 1, wj = w & 1;
  const int quad = lane >> 4, l15 = lane & 15;
  const int i0 = bi * 128;

  // One-shot A panel stage: 32 x 1KB segments, 8 per wave.
  #pragma unroll
  for (int r8 = 0; r8 < 8; ++r8) {
    const int seg = w * 8 + r8;
    const unsigned char* src = ph + (size_t)bi * 32768 + seg * 1024 + lane * 16;
    load_lds16(src, smem + seg * 1024);
  }
  __syncthreads();   // drains A staging

  const i32x4* __restrict__ phv = (const i32x4*)ph;
  const i32x4* smemv = (const i32x4*)smem;
  const float K2 = 2.0f * LOG2E2 / (S_Q * S_Q);

  float prow[4][4];   // row partial sums, accumulated across both tiles
  #pragma unroll
  for (int m = 0; m < 4; ++m)
    #pragma unroll
    for (int r = 0; r < 4; ++r) prow[m][r] = 0.f;

  auto do_tile = [&](const int bj, const bool diag_t) {
    const int j0 = bj * 128;
    const int baseB = ((bj * 8 + wj * 4) * 4) * 64 + lane;

    float sjl[4];
    #pragma unroll
    for (int n = 0; n < 4; ++n) sjl[n] = sq[j0 + wj * 64 + n * 16 + l15];

    float csum[4] = {0.f, 0.f, 0.f, 0.f};

    // quadrant epilogue: 16 elements -> prow (registers) + column sums.
    // C/D layout: col = l15, row = quad*4+reg. No fmax (off-diag d2 >= ~260;
    // diag NaN masked after exp).
    auto epilogue = [&](const i32x4* acc, const float* si, const int m) {
      #pragma unroll
      for (int r = 0; r < 4; ++r) {
        const int gi = i0 + wi * 64 + m * 16 + quad * 4 + r;
        float p = 0.f;
        #pragma unroll
        for (int n = 0; n < 4; ++n) {
          const float d2 = fmaf(-K2, (float)acc[n][r], si[r] + sjl[n]);
          float e = __builtin_amdgcn_exp2f(-__builtin_amdgcn_sqrtf(d2));
          if (diag_t && gi == j0 + wj * 64 + n * 16 + l15) e = 0.f;  // diag mask
          p += e;
          csum[n] += e;
        }
        prow[m][r] += p;
      }
    };

    // two paired-quadrant passes: quadrants (0,1) then (2,3). Per s-chunk,
    // 4 B-fragment loads feed 8 MFMAs (both quadrants share bf[s]) -- B
    // reload events halve vs per-quadrant streaming, and pass-1's loads
    // overlap pass-0's epilogues.
    #pragma unroll
    for (int p = 0; p < 2; ++p) {
      const int m0 = 2 * p, m1 = m0 + 1;
      float si0[4], si1[4];   // issued ~600cy before epilogue use
      #pragma unroll
      for (int r = 0; r < 4; ++r) {
        si0[r] = sq[i0 + wi * 64 + m0 * 16 + quad * 4 + r];
        si1[r] = sq[i0 + wi * 64 + m1 * 16 + quad * 4 + r];
      }
      i32x4 acc0[4], acc1[4];
      #pragma unroll
      for (int n = 0; n < 4; ++n) {
        acc0[n] = (i32x4){0, 0, 0, 0};
        acc1[n] = (i32x4){0, 0, 0, 0};
      }
      #pragma unroll
      for (int s = 0; s < 4; ++s) {
        i32x4 bf[4];
        #pragma unroll
        for (int n = 0; n < 4; ++n) bf[n] = phv[baseB + (n * 4 + s) * 64];
        const i32x4 ah0 = smemv[(size_t)((wi * 4 + m0) * 4 + s) * 64 + lane];
        const i32x4 ah1 = smemv[(size_t)((wi * 4 + m1) * 4 + s) * 64 + lane];
        #pragma unroll
        for (int n = 0; n < 4; ++n)
          acc0[n] = __builtin_amdgcn_mfma_i32_16x16x64_i8(ah0, bf[n], acc0[n], 0, 0, 0);
        #pragma unroll
        for (int n = 0; n < 4; ++n)
          acc1[n] = __builtin_amdgcn_mfma_i32_16x16x64_i8(ah1, bf[n], acc1[n], 0, 0, 0);
      }
      epilogue(acc0, si0, m0);
      epilogue(acc1, si1, m1);
    }

    if (!diag_t) {
      // column sums -> symmetric contribution S[j] += sum_i exp(-d_ij)
      #pragma unroll
      for (int n = 0; n < 4; ++n) {
        float c2 = csum[n];
        c2 += __shfl_xor(c2, 16, 64);
        c2 += __shfl_xor(c2, 32, 64);
        if (quad == 0) atomicAdd(&S[j0 + wj * 64 + n * 16 + l15], c2);
      }
    }
  };

  if (bj0 == bi) do_tile(bi, true); else do_tile(bj0, false);
  if (bj0 + 1 < NB) do_tile(bj0 + 1, false);

  __syncthreads();   // all waves done reading A before scratch reuse

  // Row reduction: LDS transpose of prow, one atomic set per block.
  const int wbase = w * 1088;  // 64 rows x 17 floats per wave
  #pragma unroll
  for (int m = 0; m < 4; ++m)
    #pragma unroll
    for (int r = 0; r < 4; ++r)
      swp[wbase + (m * 16 + quad * 4 + r) * 17 + l15] = prow[m][r];
  float rs = 0.f;
  #pragma unroll
  for (int j = 0; j < 16; ++j) rs += swp[wbase + lane * 17 + j];
  atomicAdd(&S[i0 + wi * 64 + lane], rs);
}

// Fused finalize: 32 blocks, per-block partials -> device-scope double
// atomics; last-ticket block emits the scalar. Release ordering: the
// __threadfence between the totals-add and the ticket-add guarantees every
// block's totals are visible before its ticket increment; the winner
// (ticket==31) therefore reads complete totals (atomic reads, L2-coherent).
__global__ __launch_bounds__(256) void finalize_fused(
    const float* __restrict__ S0, const float* __restrict__ S1,
    const float* __restrict__ align_part,
    double* __restrict__ totals, int* __restrict__ ticket,
    float* __restrict__ out, int n) {
  __shared__ float shl[4], sha[4];
  const int t = threadIdx.x, lane = t & 63, w = t >> 6;
  const int idx = blockIdx.x * 256 + t;
  float lg = __logf(S0[idx]) + __logf(S1[idx]);
  float al = align_part[idx];
  #pragma unroll
  for (int o = 1; o < 64; o <<= 1) {
    lg += __shfl_xor(lg, o, 64);
    al += __shfl_xor(al, o, 64);
  }
  if (lane == 0) { shl[w] = lg; sha[w] = al; }
  __syncthreads();
  if (t == 0) {
    const double pl = (double)(shl[0] + shl[1] + shl[2] + shl[3]);
    const double pa = (double)(sha[0] + sha[1] + sha[2] + sha[3]);
    atomicAdd(&totals[0], pl);
    atomicAdd(&totals[1], pa);
    __threadfence();
    const int old = atomicAdd(ticket, 1);
    if (old == (int)gridDim.x - 1) {
      const double lgt = atomicAdd(&totals[0], 0.0);   // atomic read
      const double alt = atomicAdd(&totals[1], 0.0);
      const double align = alt / (double)n;
      const double entropy = 0.5 * lgt / (double)n - log((double)(n - 1));
      out[0] = (float)(align + entropy);
    }
  }
}

extern "C" void kernel_launch(void* const* d_in, const int* in_sizes, int n_in,
                              void* d_out, int out_size, void* d_ws, size_t ws_size,
                              hipStream_t stream) {
  const float* v0 = (const float*)d_in[0];
  const float* v1 = (const float*)d_in[1];
  float* out = (float*)d_out;
  const int n = in_sizes[0] / D_DIM;  // 8192

  float* ws         = (float*)d_ws;
  float* sq0        = ws;             // n f32 (prescaled by log2e^2)
  float* sq1        = ws + n;
  float* S0         = ws + 2 * n;
  float* S1         = ws + 3 * n;
  float* align_part = ws + 4 * n;
  double* totals    = (double*)(ws + 5 * n);      // 2 doubles (16B-aligned)
  int* ticket       = (int*)(ws + 5 * n + 4);
  // packed i8 planes, 16B-aligned (5n+64 floats from base)
  unsigned char* ph0 = (unsigned char*)(ws + 5 * n + 64);  // n*256 i8 = 2 MB
  unsigned char* ph1 = ph0 + (size_t)n * D_DIM;            // 2 MB

  prep<<<n / 16, 256, 0, stream>>>(v0, v1, ph0, ph1, sq0, sq1, S0, S1,
                                   align_part, totals, ticket);

  dim3 grid(NSEG, 2);
  entropy_tile<<<grid, 256, 0, stream>>>(ph0, ph1, sq0, sq1, S0, S1);

  finalize_fused<<<n / 256, 256, 0, stream>>>(S0, S1, align_part, totals,
                                              ticket, out, n);
}

// Round 6
// 109.663 us; speedup vs baseline: 1.5677x; 1.5677x over previous
//
#include <hip/hip_runtime.h>
#include <math.h>

// N=8192 rows, D=256, fp32 in, scalar fp32 out.
// out = mean_i ||v0_i-v1_i|| + 0.5*(mean_i log S0_i + mean_i log S1_i) - log(N-1)
// S_i = sum_{j!=i} exp(-sqrt(max(sq_i+sq_j-2*z_i.z_j,0)))
//
// Round 20: r19's paired-quadrant body WITHOUT the launch_bounds pin. r19
// post-mortem: __launch_bounds__(256,5) capped the unified VGPR+AGPR file at
// 102 -> spill cascade (VGPR_Count 48, 335MB scratch traffic, 110us). The
// pairing itself was never tested. Model: per wave-tile 6600cy wall vs
// ~2000cy issue work; gap == 16 exposed ~270cy L2 stalls on bf reloads per
// tile. Pairing 2 quadrants per B-pass halves stall events (4 loads feed 8
// MFMAs) and pass-1 loads overlap pass-0 epilogues. Allocator unpinned; live
// set ~100-115 regs. Fused finalize + 2-tile/1056 grid retained.

#define D_DIM 256
#define NB 64                 // 8192/128 panels
#define NSEG 1056             // sum over rows bi of ceil((64-bi)/2)
#define S_Q 26.0f             // i8 quant scale
#define LOG2E2 2.0813689810f  // (log2 e)^2
#define LP 65                 // padded LDS pitch in float4 (prep)

typedef int i32x4 __attribute__((ext_vector_type(4)));
typedef unsigned int u32;
#define AS1 __attribute__((address_space(1)))
#define AS3 __attribute__((address_space(3)))

__device__ inline void load_lds16(const void* g, void* l) {
  __builtin_amdgcn_global_load_lds((const AS1 u32*)g, (AS3 u32*)l, 16, 0, 0);
}

__device__ inline int q8(float x) {
  return __float2int_rn(fminf(fmaxf(x * S_Q, -127.0f), 127.0f));
}
__device__ inline u32 q8x4(const float4 f) {
  return (u32)(q8(f.x) & 255) | ((u32)(q8(f.y) & 255) << 8) |
         ((u32)(q8(f.z) & 255) << 16) | ((u32)(q8(f.w) & 255) << 24);
}

// G(M) = sum_{L=1..M} ceil(L/2); segment-count prefix helper.
__device__ inline int Gfun(int M) {
  const int m = M >> 1;
  return (M & 1) ? (m + 1) * (m + 1) : m * (m + 1);
}

// One block per 16-row tile R. Stages both views' rows in LDS (padded pitch),
// emits packed fragment-ordered i8 planes, computes prescaled sq norms +
// align parts, zeroes S. Block 0 also zeroes the finalize totals/ticket.
// Plane layout: 16B chunk index (R*4 + s)*64 + q*16 + rr holds elements
// (row = R*16 + rr, k = s*64 + q*16 + j), j=0..15 -- one lane-operand of
// mfma_i32_16x16x64_i8 per chunk; one wave-fragment per 1KB block.
__global__ __launch_bounds__(256) void prep(
    const float* __restrict__ v0, const float* __restrict__ v1,
    unsigned char* __restrict__ ph0, unsigned char* __restrict__ ph1,
    float* __restrict__ sq0, float* __restrict__ sq1,
    float* __restrict__ S0, float* __restrict__ S1,
    float* __restrict__ align_part,
    double* __restrict__ totals, int* __restrict__ ticket) {
  __shared__ float4 l0[16 * LP], l1[16 * LP];   // 16 rows, padded pitch
  __shared__ float red0[4][16], red1[4][16], red2[4][16];
  const int R = blockIdx.x;
  const int t = threadIdx.x;

  if (R == 0 && t == 0) { totals[0] = 0.0; totals[1] = 0.0; ticket[0] = 0; }

  // coalesced load: 16 rows x 64 float4 per view (stored at padded pitch)
  #pragma unroll
  for (int p = 0; p < 4; ++p) {
    const int slot = t + p * 256;
    const int r = slot >> 6, col = slot & 63;
    const size_t g = (size_t)(R * 16 + r) * 64 + col;
    l0[r * LP + col] = ((const float4*)v0)[g];
    l1[r * LP + col] = ((const float4*)v1)[g];
  }
  __syncthreads();

  // quant+pack: thread t -> row rr = t&15, k-group c = t>>4 (16 elements)
  {
    const int rr = t & 15, c = t >> 4;
    const int s = c >> 2, q = c & 3;
    const int li = rr * LP + c * 4;       // float4 index of k = c*16
    uint4 u0, u1;
    u0.x = q8x4(l0[li + 0]); u0.y = q8x4(l0[li + 1]);
    u0.z = q8x4(l0[li + 2]); u0.w = q8x4(l0[li + 3]);
    u1.x = q8x4(l1[li + 0]); u1.y = q8x4(l1[li + 1]);
    u1.z = q8x4(l1[li + 2]); u1.w = q8x4(l1[li + 3]);
    const size_t dst = (size_t)(R * 4 + s) * 64 + q * 16 + rr;
    ((uint4*)ph0)[dst] = u0;
    ((uint4*)ph1)[dst] = u1;
  }

  // norms: thread t sums 16 elements of row (t&15), segment (t>>4)
  {
    const int rr = t & 15;
    const int base = rr * LP + (t >> 4) * 4;
    float s0p = 0.f, s1p = 0.f, s2p = 0.f;
    #pragma unroll
    for (int c = 0; c < 4; ++c) {
      const float4 a = l0[base + c], b = l1[base + c];
      s0p += a.x * a.x + a.y * a.y + a.z * a.z + a.w * a.w;
      s1p += b.x * b.x + b.y * b.y + b.z * b.z + b.w * b.w;
      const float dx = a.x - b.x, dy = a.y - b.y, dz = a.z - b.z, dw = a.w - b.w;
      s2p += dx * dx + dy * dy + dz * dz + dw * dw;
    }
    s0p += __shfl_xor(s0p, 16, 64); s0p += __shfl_xor(s0p, 32, 64);
    s1p += __shfl_xor(s1p, 16, 64); s1p += __shfl_xor(s1p, 32, 64);
    s2p += __shfl_xor(s2p, 16, 64); s2p += __shfl_xor(s2p, 32, 64);
    const int w = t >> 6, lane = t & 63;
    if (lane < 16) { red0[w][lane] = s0p; red1[w][lane] = s1p; red2[w][lane] = s2p; }
  }
  __syncthreads();
  if (t < 16) {
    const int row = R * 16 + t;
    const float a0 = red0[0][t] + red0[1][t] + red0[2][t] + red0[3][t];
    const float a1 = red1[0][t] + red1[1][t] + red1[2][t] + red1[3][t];
    const float a2 = red2[0][t] + red2[1][t] + red2[2][t] + red2[3][t];
    sq0[row] = a0 * LOG2E2;               // prescaled: epilogue works in log2 units
    sq1[row] = a1 * LOG2E2;
    align_part[row] = sqrtf(a2);
    S0[row] = 0.0f;
    S1[row] = 0.0f;
  }
}

// Persistent 2-tile row segments; grid (NSEG, 2=view). 4 waves in 2x2.
// Per tile: two paired-quadrant passes; each pass streams the 16 B
// fragments ONCE (4 loads per s-chunk feeding 8 MFMAs into two quadrant
// accumulators), then runs both quadrants' epilogues -- which overlap the
// next pass's B loads (no barriers inside or between tiles).
__global__ __launch_bounds__(256) void entropy_tile(
    const unsigned char* __restrict__ ph0, const unsigned char* __restrict__ ph1,
    const float* __restrict__ sq0, const float* __restrict__ sq1,
    float* __restrict__ S0, float* __restrict__ S1) {
  const unsigned char* __restrict__ ph = blockIdx.y ? ph1 : ph0;
  const float* __restrict__ sq = blockIdx.y ? sq1 : sq0;
  float* __restrict__ S        = blockIdx.y ? S1 : S0;

  // decode segment -> (bi, q): row bi has ceil((64-bi)/2) segments;
  // prefix P(bi) = NSEG - G(64-bi).
  const int lin = blockIdx.x;
  int bi = 0;
  while (NSEG - Gfun(64 - (bi + 1)) <= lin) ++bi;
  const int q = lin - (NSEG - Gfun(64 - bi));
  const int bj0 = bi + 2 * q;

  // 32 KB: the A panel (i8, fragment order). Front 17408 B reused as epilogue
  // scratch (guarded by the post-tiles barrier).
  __shared__ __align__(16) char smem[32768];
  float* swp = (float*)smem;

  const int t = threadIdx.x, lane = t & 63, w = t >> 6;
  const int wi = w >> 1, wj = w & 1;
  const int quad = lane >> 4, l15 = lane & 15;
  const int i0 = bi * 128;

  // One-shot A panel stage: 32 x 1KB segments, 8 per wave.
  #pragma unroll
  for (int r8 = 0; r8 < 8; ++r8) {
    const int seg = w * 8 + r8;
    const unsigned char* src = ph + (size_t)bi * 32768 + seg * 1024 + lane * 16;
    load_lds16(src, smem + seg * 1024);
  }
  __syncthreads();   // drains A staging

  const i32x4* __restrict__ phv = (const i32x4*)ph;
  const i32x4* smemv = (const i32x4*)smem;
  const float K2 = 2.0f * LOG2E2 / (S_Q * S_Q);

  float prow[4][4];   // row partial sums, accumulated across both tiles
  #pragma unroll
  for (int m = 0; m < 4; ++m)
    #pragma unroll
    for (int r = 0; r < 4; ++r) prow[m][r] = 0.f;

  auto do_tile = [&](const int bj, const bool diag_t) {
    const int j0 = bj * 128;
    const int baseB = ((bj * 8 + wj * 4) * 4) * 64 + lane;

    float sjl[4];
    #pragma unroll
    for (int n = 0; n < 4; ++n) sjl[n] = sq[j0 + wj * 64 + n * 16 + l15];

    float csum[4] = {0.f, 0.f, 0.f, 0.f};

    // quadrant epilogue: 16 elements -> prow (registers) + column sums.
    // C/D layout: col = l15, row = quad*4+reg. No fmax (off-diag d2 >= ~260;
    // diag NaN masked after exp).
    auto epilogue = [&](const i32x4* acc, const float* si, const int m) {
      #pragma unroll
      for (int r = 0; r < 4; ++r) {
        const int gi = i0 + wi * 64 + m * 16 + quad * 4 + r;
        float p = 0.f;
        #pragma unroll
        for (int n = 0; n < 4; ++n) {
          const float d2 = fmaf(-K2, (float)acc[n][r], si[r] + sjl[n]);
          float e = __builtin_amdgcn_exp2f(-__builtin_amdgcn_sqrtf(d2));
          if (diag_t && gi == j0 + wj * 64 + n * 16 + l15) e = 0.f;  // diag mask
          p += e;
          csum[n] += e;
        }
        prow[m][r] += p;
      }
    };

    // two paired-quadrant passes: quadrants (0,1) then (2,3). Per s-chunk,
    // 4 B-fragment loads feed 8 MFMAs (both quadrants share bf[s]) -- B
    // reload events halve vs per-quadrant streaming, and pass-1's loads
    // overlap pass-0's epilogues.
    #pragma unroll
    for (int p = 0; p < 2; ++p) {
      const int m0 = 2 * p, m1 = m0 + 1;
      float si0[4], si1[4];   // issued ~600cy before epilogue use
      #pragma unroll
      for (int r = 0; r < 4; ++r) {
        si0[r] = sq[i0 + wi * 64 + m0 * 16 + quad * 4 + r];
        si1[r] = sq[i0 + wi * 64 + m1 * 16 + quad * 4 + r];
      }
      i32x4 acc0[4], acc1[4];
      #pragma unroll
      for (int n = 0; n < 4; ++n) {
        acc0[n] = (i32x4){0, 0, 0, 0};
        acc1[n] = (i32x4){0, 0, 0, 0};
      }
      #pragma unroll
      for (int s = 0; s < 4; ++s) {
        i32x4 bf[4];
        #pragma unroll
        for (int n = 0; n < 4; ++n) bf[n] = phv[baseB + (n * 4 + s) * 64];
        const i32x4 ah0 = smemv[(size_t)((wi * 4 + m0) * 4 + s) * 64 + lane];
        const i32x4 ah1 = smemv[(size_t)((wi * 4 + m1) * 4 + s) * 64 + lane];
        #pragma unroll
        for (int n = 0; n < 4; ++n)
          acc0[n] = __builtin_amdgcn_mfma_i32_16x16x64_i8(ah0, bf[n], acc0[n], 0, 0, 0);
        #pragma unroll
        for (int n = 0; n < 4; ++n)
          acc1[n] = __builtin_amdgcn_mfma_i32_16x16x64_i8(ah1, bf[n], acc1[n], 0, 0, 0);
      }
      epilogue(acc0, si0, m0);
      epilogue(acc1, si1, m1);
    }

    if (!diag_t) {
      // column sums -> symmetric contribution S[j] += sum_i exp(-d_ij)
      #pragma unroll
      for (int n = 0; n < 4; ++n) {
        float c2 = csum[n];
        c2 += __shfl_xor(c2, 16, 64);
        c2 += __shfl_xor(c2, 32, 64);
        if (quad == 0) atomicAdd(&S[j0 + wj * 64 + n * 16 + l15], c2);
      }
    }
  };

  if (bj0 == bi) do_tile(bi, true); else do_tile(bj0, false);
  if (bj0 + 1 < NB) do_tile(bj0 + 1, false);

  __syncthreads();   // all waves done reading A before scratch reuse

  // Row reduction: LDS transpose of prow, one atomic set per block.
  const int wbase = w * 1088;  // 64 rows x 17 floats per wave
  #pragma unroll
  for (int m = 0; m < 4; ++m)
    #pragma unroll
    for (int r = 0; r < 4; ++r)
      swp[wbase + (m * 16 + quad * 4 + r) * 17 + l15] = prow[m][r];
  float rs = 0.f;
  #pragma unroll
  for (int j = 0; j < 16; ++j) rs += swp[wbase + lane * 17 + j];
  atomicAdd(&S[i0 + wi * 64 + lane], rs);
}

// Fused finalize: 32 blocks, per-block partials -> device-scope double
// atomics; last-ticket block emits the scalar. Release ordering: the
// __threadfence between the totals-add and the ticket-add guarantees every
// block's totals are visible before its ticket increment; the winner
// (ticket==31) therefore reads complete totals (atomic reads, L2-coherent).
__global__ __launch_bounds__(256) void finalize_fused(
    const float* __restrict__ S0, const float* __restrict__ S1,
    const float* __restrict__ align_part,
    double* __restrict__ totals, int* __restrict__ ticket,
    float* __restrict__ out, int n) {
  __shared__ float shl[4], sha[4];
  const int t = threadIdx.x, lane = t & 63, w = t >> 6;
  const int idx = blockIdx.x * 256 + t;
  float lg = __logf(S0[idx]) + __logf(S1[idx]);
  float al = align_part[idx];
  #pragma unroll
  for (int o = 1; o < 64; o <<= 1) {
    lg += __shfl_xor(lg, o, 64);
    al += __shfl_xor(al, o, 64);
  }
  if (lane == 0) { shl[w] = lg; sha[w] = al; }
  __syncthreads();
  if (t == 0) {
    const double pl = (double)(shl[0] + shl[1] + shl[2] + shl[3]);
    const double pa = (double)(sha[0] + sha[1] + sha[2] + sha[3]);
    atomicAdd(&totals[0], pl);
    atomicAdd(&totals[1], pa);
    __threadfence();
    const int old = atomicAdd(ticket, 1);
    if (old == (int)gridDim.x - 1) {
      const double lgt = atomicAdd(&totals[0], 0.0);   // atomic read
      const double alt = atomicAdd(&totals[1], 0.0);
      const double align = alt / (double)n;
      const double entropy = 0.5 * lgt / (double)n - log((double)(n - 1));
      out[0] = (float)(align + entropy);
    }
  }
}

extern "C" void kernel_launch(void* const* d_in, const int* in_sizes, int n_in,
                              void* d_out, int out_size, void* d_ws, size_t ws_size,
                              hipStream_t stream) {
  const float* v0 = (const float*)d_in[0];
  const float* v1 = (const float*)d_in[1];
  float* out = (float*)d_out;
  const int n = in_sizes[0] / D_DIM;  // 8192

  float* ws         = (float*)d_ws;
  float* sq0        = ws;             // n f32 (prescaled by log2e^2)
  float* sq1        = ws + n;
  float* S0         = ws + 2 * n;
  float* S1         = ws + 3 * n;
  float* align_part = ws + 4 * n;
  double* totals    = (double*)(ws + 5 * n);      // 2 doubles (16B-aligned)
  int* ticket       = (int*)(ws + 5 * n + 4);
  // packed i8 planes, 16B-aligned (5n+64 floats from base)
  unsigned char* ph0 = (unsigned char*)(ws + 5 * n + 64);  // n*256 i8 = 2 MB
  unsigned char* ph1 = ph0 + (size_t)n * D_DIM;            // 2 MB

  prep<<<n / 16, 256, 0, stream>>>(v0, v1, ph0, ph1, sq0, sq1, S0, S1,
                                   align_part, totals, ticket);

  dim3 grid(NSEG, 2);
  entropy_tile<<<grid, 256, 0, stream>>>(ph0, ph1, sq0, sq1, S0, S1);

  finalize_fused<<<n / 256, 256, 0, stream>>>(S0, S1, align_part, totals,
                                              ticket, out, n);
}